// Round 1
// baseline (230.252 us; speedup 1.0000x reference)
//
#include <hip/hip_runtime.h>
#include <math.h>

#define B 16
#define N 10000
#define E 160000
#define CAP 96   // per-dst bucket capacity; deg ~ Poisson(16), P(deg>96) ~ 0

// float -> bf16 (RNE) stored as ushort
__device__ __forceinline__ ushort f2bf(float v) {
    uint u = __float_as_uint(v);
    u = (u + 0x7fffu + ((u >> 16) & 1u)) >> 16;
    return (ushort)u;
}
__device__ __forceinline__ float bf2f(ushort u) { return __uint_as_float(((uint)u) << 16); }
__device__ __forceinline__ float bf2f_lo(uint u) { return __uint_as_float(u << 16); }
__device__ __forceinline__ float bf2f_hi(uint u) { return __uint_as_float(u & 0xffff0000u); }
// bucket payload: (ew_q18 << 14) | src ; decode with midpoint
__device__ __forceinline__ float dec_ew(uint u) {
    return ((float)(u >> 14) + 0.5f) * (1.0f / 262144.0f);
}

// ---------------------------------------------------------------------------
// Fused prep + bucket (proven R10 phase-0 / R12): grid-stride over both
// independent workloads — scattered bucket atomics + streaming transpose.
// ---------------------------------------------------------------------------
__global__ __launch_bounds__(256)
void prep_bucket_kernel(const float* __restrict__ X,
                        const float* __restrict__ gate_w1,   // (65)
                        const int* __restrict__ ei1, const float* __restrict__ ew1,
                        const int* __restrict__ ei2, const float* __restrict__ ew2,
                        ushort* __restrict__ xt,
                        float* __restrict__ gi, float* __restrict__ gj,
                        int* __restrict__ bcount1, uint* __restrict__ bucket1,
                        int* __restrict__ bcount2, uint* __restrict__ bucket2) {
    int gtid = blockIdx.x * 256 + threadIdx.x;
    int gs = gridDim.x * 256;

    for (int t = gtid; t < 2 * E; t += gs) {
        if (t < E) {
            int d = ei1[E + t];
            int pos = atomicAdd(&bcount1[d], 1);
            if (pos < CAP) {
                uint q = (uint)(ew1[t] * 262144.0f);
                if (q > 262143u) q = 262143u;
                bucket1[d * CAP + pos] = (q << 14) | (uint)ei1[t];
            }
        } else {
            int e = t - E;
            int d = ei2[E + e];
            int pos = atomicAdd(&bcount2[d], 1);
            if (pos < CAP) {
                uint q = (uint)(ew2[e] * 262144.0f);
                if (q > 262143u) q = 262143u;
                bucket2[d * CAP + pos] = (q << 14) | (uint)ei2[e];
            }
        }
    }
    for (int t = gtid; t < N * B * 32; t += gs) {
        int c = t & 31;
        int r = t >> 5;            // n*B + b
        int b = r & 15;
        int n = r >> 4;
        float v = X[((size_t)b * N + n) * 32 + c];
        xt[t] = f2bf(v);
        float pi = v * gate_w1[c];
        float pj = v * gate_w1[32 + c];
        #pragma unroll
        for (int off = 16; off; off >>= 1) {
            pi += __shfl_xor(pi, off, 32);
            pj += __shfl_xor(pj, off, 32);
        }
        if (c == 0) { gi[r] = pi; gj[r] = pj; }
    }
}

// ---------------------------------------------------------------------------
// Fused layer 1, batch-group sliced for per-XCD L2 residency:
// grid = 4*N, bg = bid / N (slow index -> dispatch-order phase separation).
// Each block: node n, batches [4*bg, 4*bg+4). Active xt slice per phase =
// N * 4 * 32 * 2B = 2.56 MB < 4 MiB per-XCD L2 (was 10.24 MB -> thrash).
// 128 threads = 2 waves; gather map per wave: 8 c4 x 2 bl x 4 h.
// ---------------------------------------------------------------------------
__global__ __launch_bounds__(128, 8)
void agg_dense1_kernel(const float* __restrict__ X,
                       const uint2* __restrict__ xt2,     // xt as bf16x4 (8B)
                       const float* __restrict__ gi,
                       const float* __restrict__ gj,
                       const int* __restrict__ bcount,
                       const uint* __restrict__ bucket,
                       const float* __restrict__ gate_w,   // (65), [64]=wge
                       const float* __restrict__ gate_b,
                       const float* __restrict__ amp_w,    // (32)
                       const float* __restrict__ w1,       // (64,16)
                       const float* __restrict__ b1,       // (16)
                       const float* __restrict__ gate_w2,  // (33)
                       ushort* __restrict__ htb,
                       float* __restrict__ gi2, float* __restrict__ gj2) {
    __shared__ uint  s_eb[CAP];                       // packed (ew<<14)|src
    __shared__ float s_coef[CAP * 4];                 // [k][bl], 1.5 KB
    __shared__ float s_gi[4];
    __shared__ __align__(16) float s_x[4][36];        // row 144B: b128-able
    __shared__ __align__(16) float s_feat[4][36];
    __shared__ __align__(16) float s_wmT[16 * 68];    // [o][kk], row 272B

    int bid = blockIdx.x;
    int bg = bid / N;                 // 0..3 (slow index)
    int n = bid - bg * N;
    int tid = threadIdx.x;

    int cnt = bcount[n];
    int deg = cnt < CAP ? cnt : CAP;
    if (tid < deg) s_eb[tid] = bucket[n * CAP + tid];
    for (int i = tid; i < 1024; i += 128) s_wmT[(i & 15) * 68 + (i >> 4)] = w1[i];
    {
        int bl = tid >> 5, c = tid & 31;              // 4b x 32c = 128
        s_x[bl][c] = X[((size_t)(bg * 4 + bl) * N + n) * 32 + c];
    }
    if (tid < 4) s_gi[tid] = gi[n * 16 + bg * 4 + tid] + gate_b[0];
    __syncthreads();

    // Phase 1: coef[k][bl] = ew * sigmoid(gi + gj + ew*wge + gb). Edge-parallel.
    float wge = gate_w[64];
    for (int p = tid; p < deg * 4; p += 128) {
        int k = p >> 2, bl = p & 3;
        uint pr = s_eb[k];
        float w = dec_ew(pr);
        float z = s_gi[bl] + gj[(pr & 0x3FFFu) * 16 + bg * 4 + bl] + w * wge;
        s_coef[p] = w / (1.0f + __expf(-z));
    }
    __syncthreads();

    // Phase 2: gather. wave lane l: c4=l&7, bl=2*wv+((l>>3)&1), h=l>>4 (0..3).
    int wv = tid >> 6, l = tid & 63;
    int c4 = l & 7;                        // channel group: 4c4..4c4+3
    int bl = 2 * wv + ((l >> 3) & 1);      // 0..3
    int h = l >> 4;                        // slot offset 0..3
    uint boff = (uint)(bg * 4 + bl) * 8 + c4;  // uint2 idx within 1KB node block
    float a0 = 0.f, a1 = 0.f, a2 = 0.f, a3 = 0.f;
    int k = h;
    for (; k + 4 < deg; k += 8) {          // slots k, k+4
        uint p0 = s_eb[k], p1 = s_eb[k + 4];
        float c0 = s_coef[k * 4 + bl], c1 = s_coef[(k + 4) * 4 + bl];
        uint2 u0 = xt2[(p0 & 0x3FFFu) * 128u + boff];
        uint2 u1 = xt2[(p1 & 0x3FFFu) * 128u + boff];
        a0 += c0 * bf2f_lo(u0.x) + c1 * bf2f_lo(u1.x);
        a1 += c0 * bf2f_hi(u0.x) + c1 * bf2f_hi(u1.x);
        a2 += c0 * bf2f_lo(u0.y) + c1 * bf2f_lo(u1.y);
        a3 += c0 * bf2f_hi(u0.y) + c1 * bf2f_hi(u1.y);
    }
    if (k < deg) {                         // at most one leftover slot
        uint pr = s_eb[k];
        float cc = s_coef[k * 4 + bl];
        uint2 u = xt2[(pr & 0x3FFFu) * 128u + boff];
        a0 += cc * bf2f_lo(u.x); a1 += cc * bf2f_hi(u.x);
        a2 += cc * bf2f_lo(u.y); a3 += cc * bf2f_hi(u.y);
    }
    a0 += __shfl_xor(a0, 16, 64); a0 += __shfl_xor(a0, 32, 64);
    a1 += __shfl_xor(a1, 16, 64); a1 += __shfl_xor(a1, 32, 64);
    a2 += __shfl_xor(a2, 16, 64); a2 += __shfl_xor(a2, 32, 64);
    a3 += __shfl_xor(a3, 16, 64); a3 += __shfl_xor(a3, 32, 64);
    if (h == 0) {
        float inv = 1.0f / fmaxf((float)cnt, 1.0f);
        s_feat[bl][4 * c4]     = a0 * amp_w[4 * c4] * inv;
        s_feat[bl][4 * c4 + 1] = a1 * amp_w[4 * c4 + 1] * inv;
        s_feat[bl][4 * c4 + 2] = a2 * amp_w[4 * c4 + 2] * inv;
        s_feat[bl][4 * c4 + 3] = a3 * amp_w[4 * c4 + 3] * inv;
    }
    __syncthreads();

    // Phase 3: dense 64->16 (vectorized LDS), leaky, layer-2 gate dots.
    // 4 bl x 16 o = 64 outputs -> wave 0 only.
    if (tid < 64) {
        int o = tid & 15, b_l = tid >> 4;
        const float4* wr4 = (const float4*)&s_wmT[o * 68];   // 272B-aligned rows
        const float4* x4  = (const float4*)&s_x[b_l][0];     // 144B-aligned rows
        const float4* f4  = (const float4*)&s_feat[b_l][0];
        float d = b1[o];
        #pragma unroll
        for (int q = 0; q < 8; ++q) {
            float4 wvv = wr4[q],    xv = x4[q];
            float4 wf = wr4[8 + q], fv = f4[q];
            d += xv.x * wvv.x + xv.y * wvv.y + xv.z * wvv.z + xv.w * wvv.w;
            d += fv.x * wf.x + fv.y * wf.y + fv.z * wf.z + fv.w * wf.w;
        }
        d = d > 0.0f ? d : 0.01f * d;
        int b = bg * 4 + b_l;
        htb[((size_t)n * 16 + b) * 16 + o] = f2bf(d);
        float pi = d * gate_w2[o];
        float pj = d * gate_w2[16 + o];
        #pragma unroll
        for (int off = 8; off; off >>= 1) {
            pi += __shfl_xor(pi, off, 16);
            pj += __shfl_xor(pj, off, 16);
        }
        if (o == 0) { gi2[n * 16 + b] = pi; gj2[n * 16 + b] = pj; }
    }
}

// ---------------------------------------------------------------------------
// Fused layer 2, batch-group sliced: grid = 2*N, bg = bid / N.
// Each block: node n, batches [8*bg, 8*bg+8). Active htb slice per phase =
// N * 8 * 16 * 2B = 2.56 MB < 4 MiB per-XCD L2 (was 5.12 MB).
// 128 threads = 2 waves; gather map per wave: 4 c4 x 4 bl x 4 h.
// ---------------------------------------------------------------------------
__global__ __launch_bounds__(128, 8)
void agg_dense2_kernel(const ushort* __restrict__ htb,    // bf16 (self + gather)
                       const uint2* __restrict__ htb2,
                       const float* __restrict__ gi,
                       const float* __restrict__ gj,
                       const int* __restrict__ bcount,
                       const uint* __restrict__ bucket,
                       const float* __restrict__ gate_w,   // (33), [32]=wge
                       const float* __restrict__ gate_b,
                       const float* __restrict__ amp_w,    // (16)
                       const float* __restrict__ w2,       // (32,32)
                       const float* __restrict__ b2,       // (32)
                       float* __restrict__ out) {
    __shared__ uint  s_eb[CAP];
    __shared__ float s_coef[CAP * 8];                 // [k][bl], 3 KB
    __shared__ float s_gi[8];
    __shared__ __align__(16) float s_x[8][20];        // row 80B: b128-able
    __shared__ __align__(16) float s_feat[8][20];
    __shared__ __align__(16) float s_wmT[32 * 36];    // [o][kk], row 144B

    int bid = blockIdx.x;
    int bg = bid / N;                 // 0..1 (slow index)
    int n = bid - bg * N;
    int tid = threadIdx.x;

    int cnt = bcount[n];
    int deg = cnt < CAP ? cnt : CAP;
    if (tid < deg) s_eb[tid] = bucket[n * CAP + tid];
    for (int i = tid; i < 1024; i += 128) s_wmT[(i & 31) * 36 + (i >> 5)] = w2[i];
    {
        int bl = tid >> 4, c = tid & 15;              // 8b x 16c = 128
        s_x[bl][c] = bf2f(htb[(size_t)n * 256 + (bg * 8 + bl) * 16 + c]);
    }
    if (tid < 8) s_gi[tid] = gi[n * 16 + bg * 8 + tid] + gate_b[0];
    __syncthreads();

    float wge = gate_w[32];
    for (int p = tid; p < deg * 8; p += 128) {
        int k = p >> 3, bl = p & 7;
        uint pr = s_eb[k];
        float w = dec_ew(pr);
        float z = s_gi[bl] + gj[(pr & 0x3FFFu) * 16 + bg * 8 + bl] + w * wge;
        s_coef[p] = w / (1.0f + __expf(-z));
    }
    __syncthreads();

    // Gather: wave lane l: c4=l&3, bl=4*wv+((l>>2)&3), h=l>>4 (0..3).
    int wv = tid >> 6, l = tid & 63;
    int c4 = l & 3;                        // channel group: 4c4..4c4+3
    int bl = 4 * wv + ((l >> 2) & 3);      // 0..7
    int h = l >> 4;                        // slot offset 0..3
    uint boff = (uint)(bg * 8 + bl) * 4 + c4;  // uint2 idx within 512B node block
    float a0 = 0.f, a1 = 0.f, a2 = 0.f, a3 = 0.f;
    int k = h;
    for (; k + 4 < deg; k += 8) {          // slots k, k+4
        uint p0 = s_eb[k], p1 = s_eb[k + 4];
        float c0 = s_coef[k * 8 + bl], c1 = s_coef[(k + 4) * 8 + bl];
        uint2 u0 = htb2[(p0 & 0x3FFFu) * 64u + boff];
        uint2 u1 = htb2[(p1 & 0x3FFFu) * 64u + boff];
        a0 += c0 * bf2f_lo(u0.x) + c1 * bf2f_lo(u1.x);
        a1 += c0 * bf2f_hi(u0.x) + c1 * bf2f_hi(u1.x);
        a2 += c0 * bf2f_lo(u0.y) + c1 * bf2f_lo(u1.y);
        a3 += c0 * bf2f_hi(u0.y) + c1 * bf2f_hi(u1.y);
    }
    if (k < deg) {                         // at most one leftover slot
        uint pr = s_eb[k];
        float cc = s_coef[k * 8 + bl];
        uint2 u = htb2[(pr & 0x3FFFu) * 64u + boff];
        a0 += cc * bf2f_lo(u.x); a1 += cc * bf2f_hi(u.x);
        a2 += cc * bf2f_lo(u.y); a3 += cc * bf2f_hi(u.y);
    }
    a0 += __shfl_xor(a0, 16, 64); a0 += __shfl_xor(a0, 32, 64);
    a1 += __shfl_xor(a1, 16, 64); a1 += __shfl_xor(a1, 32, 64);
    a2 += __shfl_xor(a2, 16, 64); a2 += __shfl_xor(a2, 32, 64);
    a3 += __shfl_xor(a3, 16, 64); a3 += __shfl_xor(a3, 32, 64);
    if (h == 0) {
        float inv = 1.0f / fmaxf((float)cnt, 1.0f);
        s_feat[bl][4 * c4]     = a0 * amp_w[4 * c4] * inv;
        s_feat[bl][4 * c4 + 1] = a1 * amp_w[4 * c4 + 1] * inv;
        s_feat[bl][4 * c4 + 2] = a2 * amp_w[4 * c4 + 2] * inv;
        s_feat[bl][4 * c4 + 3] = a3 * amp_w[4 * c4 + 3] * inv;
    }
    __syncthreads();

    // Dense 32->32 (vectorized LDS); thread (bl, o) produces (o, o+16).
    // 8 bl x 16 o = 128 threads, all active. out (B,N,32).
    {
        int o = tid & 15, b_l = tid >> 4;
        const float4* wr0 = (const float4*)&s_wmT[o * 36];          // 144B rows
        const float4* wr1 = (const float4*)&s_wmT[(o + 16) * 36];
        const float4* x4  = (const float4*)&s_x[b_l][0];            // 80B rows
        const float4* f4  = (const float4*)&s_feat[b_l][0];
        float d0 = b2[o], d1 = b2[o + 16];
        #pragma unroll
        for (int q = 0; q < 4; ++q) {
            float4 xv = x4[q], fv = f4[q];
            float4 w0a = wr0[q], w0b = wr0[4 + q];
            float4 w1a = wr1[q], w1b = wr1[4 + q];
            d0 += xv.x * w0a.x + xv.y * w0a.y + xv.z * w0a.z + xv.w * w0a.w;
            d0 += fv.x * w0b.x + fv.y * w0b.y + fv.z * w0b.z + fv.w * w0b.w;
            d1 += xv.x * w1a.x + xv.y * w1a.y + xv.z * w1a.z + xv.w * w1a.w;
            d1 += fv.x * w1b.x + fv.y * w1b.y + fv.z * w1b.z + fv.w * w1b.w;
        }
        size_t ob = ((size_t)(bg * 8 + b_l) * N + n) * 32;
        out[ob + o] = d0;
        out[ob + o + 16] = d1;
    }
}

// ---------------------------------------------------------------------------
extern "C" void kernel_launch(void* const* d_in, const int* in_sizes, int n_in,
                              void* d_out, int out_size, void* d_ws, size_t ws_size,
                              hipStream_t stream) {
    const float* X       = (const float*)d_in[0];
    const int*   ei1     = (const int*)  d_in[1];   // src=ei1, dst=ei1+E
    const float* ew1     = (const float*)d_in[2];
    const int*   ei2     = (const int*)  d_in[4];
    const float* ew2     = (const float*)d_in[5];
    const float* amp_w1  = (const float*)d_in[7];
    const float* gate_w1 = (const float*)d_in[8];
    const float* gate_b1 = (const float*)d_in[9];
    const float* w1      = (const float*)d_in[10];
    const float* b1      = (const float*)d_in[11];
    const float* amp_w2  = (const float*)d_in[12];
    const float* gate_w2 = (const float*)d_in[13];
    const float* gate_b2 = (const float*)d_in[14];
    const float* w2      = (const float*)d_in[15];
    const float* b2      = (const float*)d_in[16];
    float* out = (float*)d_out;

    // ws layout
    char* p = (char*)d_ws;
    ushort* xt     = (ushort*)p; p += (size_t)N * B * 32 * sizeof(ushort); // 10.24 MB
    ushort* htb    = (ushort*)p; p += (size_t)N * B * 16 * sizeof(ushort); // 5.12 MB
    float* gi1     = (float*)p;  p += (size_t)N * B * sizeof(float);
    float* gj1     = (float*)p;  p += (size_t)N * B * sizeof(float);
    float* gi2     = (float*)p;  p += (size_t)N * B * sizeof(float);
    float* gj2     = (float*)p;  p += (size_t)N * B * sizeof(float);
    uint*  bucket1 = (uint*)p;   p += (size_t)N * CAP * sizeof(uint);      // 3.84 MB
    uint*  bucket2 = (uint*)p;   p += (size_t)N * CAP * sizeof(uint);      // 3.84 MB
    int*   bcount1 = (int*)p;    p += (size_t)N * sizeof(int);
    int*   bcount2 = (int*)p;    p += (size_t)N * sizeof(int);

    hipMemsetAsync(bcount1, 0, 2 * (size_t)N * sizeof(int), stream);
    prep_bucket_kernel<<<2048, 256, 0, stream>>>(
        X, gate_w1, ei1, ew1, ei2, ew2, xt, gi1, gj1,
        bcount1, bucket1, bcount2, bucket2);

    // 4 batch-groups of 4: per-phase gather slice 2.56 MB (L2-resident)
    agg_dense1_kernel<<<4 * N, 128, 0, stream>>>(
        X, (const uint2*)xt, gi1, gj1, bcount1, bucket1,
        gate_w1, gate_b1, amp_w1, w1, b1, gate_w2, htb, gi2, gj2);

    // 2 batch-groups of 8: per-phase gather slice 2.56 MB (L2-resident)
    agg_dense2_kernel<<<2 * N, 128, 0, stream>>>(
        htb, (const uint2*)htb, gi2, gj2, bcount2, bucket2,
        gate_w2, gate_b2, amp_w2, w2, b2, out);
}

// Round 2
// 199.933 us; speedup vs baseline: 1.1516x; 1.1516x over previous
//
#include <hip/hip_runtime.h>
#include <math.h>

#define B 16
#define N 10000
#define E 160000
#define CAP 96   // per-dst bucket capacity; deg ~ Poisson(16), P(deg>96) ~ 0

// float -> bf16 (RNE) stored as ushort
__device__ __forceinline__ ushort f2bf(float v) {
    uint u = __float_as_uint(v);
    u = (u + 0x7fffu + ((u >> 16) & 1u)) >> 16;
    return (ushort)u;
}
__device__ __forceinline__ float bf2f(ushort u) { return __uint_as_float(((uint)u) << 16); }
__device__ __forceinline__ float bf2f_lo(uint u) { return __uint_as_float(u << 16); }
__device__ __forceinline__ float bf2f_hi(uint u) { return __uint_as_float(u & 0xffff0000u); }
// bucket payload: (ew_q18 << 14) | src ; decode with midpoint
__device__ __forceinline__ float dec_ew(uint u) {
    return ((float)(u >> 14) + 0.5f) * (1.0f / 262144.0f);
}

// ---------------------------------------------------------------------------
// Prep: edge bucketing (atomics) + row-per-thread transpose (float4 in,
// uint4 bf16 out, serial gate dots - no shuffles) + weight transposes.
// ---------------------------------------------------------------------------
__global__ __launch_bounds__(256)
void prep_bucket_kernel(const float* __restrict__ X,
                        const float* __restrict__ gate_w1,   // (65)
                        const int* __restrict__ ei1, const float* __restrict__ ew1,
                        const int* __restrict__ ei2, const float* __restrict__ ew2,
                        const float* __restrict__ w1,        // (64,16)
                        const float* __restrict__ w2,        // (32,32)
                        ushort* __restrict__ xt,
                        float* __restrict__ gi, float* __restrict__ gj,
                        float* __restrict__ w1T, float* __restrict__ w2T,
                        int* __restrict__ bcount1, uint* __restrict__ bucket1,
                        int* __restrict__ bcount2, uint* __restrict__ bucket2) {
    int gtid = blockIdx.x * 256 + threadIdx.x;
    int gs = gridDim.x * 256;

    for (int t = gtid; t < 2 * E; t += gs) {
        if (t < E) {
            int d = ei1[E + t];
            int pos = atomicAdd(&bcount1[d], 1);
            if (pos < CAP) {
                uint q = (uint)(ew1[t] * 262144.0f);
                if (q > 262143u) q = 262143u;
                bucket1[d * CAP + pos] = (q << 14) | (uint)ei1[t];
            }
        } else {
            int e = t - E;
            int d = ei2[E + e];
            int pos = atomicAdd(&bcount2[d], 1);
            if (pos < CAP) {
                uint q = (uint)(ew2[e] * 262144.0f);
                if (q > 262143u) q = 262143u;
                bucket2[d * CAP + pos] = (q << 14) | (uint)ei2[e];
            }
        }
    }

    // one thread per (b,n) row: b slow -> consecutive threads read consecutive
    // X rows (fully coalesced); xt/gi/gj stores scattered at 64B granularity.
    for (int t = gtid; t < N * B; t += gs) {
        int b = t / N;
        int n = t - b * N;
        int r = n * 16 + b;                       // xt/gi/gj row index
        const float4* xr = (const float4*)(X + ((size_t)b * N + n) * 32);
        float pi = 0.f, pj = 0.f;
        union { uint u[16]; uint4 v4[4]; } pk;
        #pragma unroll
        for (int q = 0; q < 8; ++q) {
            float4 v = xr[q];
            pi += v.x * gate_w1[4*q]   + v.y * gate_w1[4*q+1]
                + v.z * gate_w1[4*q+2] + v.w * gate_w1[4*q+3];
            pj += v.x * gate_w1[32+4*q]   + v.y * gate_w1[32+4*q+1]
                + v.z * gate_w1[32+4*q+2] + v.w * gate_w1[32+4*q+3];
            pk.u[2*q]   = (uint)f2bf(v.x) | ((uint)f2bf(v.y) << 16);
            pk.u[2*q+1] = (uint)f2bf(v.z) | ((uint)f2bf(v.w) << 16);
        }
        uint4* dst = (uint4*)(xt + (size_t)r * 32);
        dst[0] = pk.v4[0]; dst[1] = pk.v4[1];
        dst[2] = pk.v4[2]; dst[3] = pk.v4[3];
        gi[r] = pi; gj[r] = pj;
    }

    // weight transposes: w1T[o][kk] (16x64), w2T[o][kk] (32x32)
    if (gtid < 1024) {
        w1T[(gtid & 15) * 64 + (gtid >> 4)] = w1[gtid];
        w2T[(gtid & 31) * 32 + (gtid >> 5)] = w2[gtid];
    }
}

// ---------------------------------------------------------------------------
// Fused layer 1: one node per block, 256 threads (R9 structure, uint4 gather).
// Lane map per wave: c8=l&3 (8ch), b=4*wv+((l>>2)&3), h=l>>4 (slot depth 4).
// Gather coalescing: 16 consecutive lanes cover 256B contiguous per slot.
// ---------------------------------------------------------------------------
__global__ __launch_bounds__(256, 8)
void agg_dense1_kernel(const float* __restrict__ X,
                       const uint4* __restrict__ xt4,     // bf16x8 (16B)
                       const float* __restrict__ gi,
                       const float* __restrict__ gj,
                       const int* __restrict__ bcount,
                       const uint* __restrict__ bucket,
                       const float* __restrict__ gate_w,   // (65), [64]=wge
                       const float* __restrict__ gate_b,
                       const float* __restrict__ amp_w,    // (32)
                       const float* __restrict__ w1T,      // (16,64) [o][kk]
                       const float* __restrict__ b1,       // (16)
                       const float* __restrict__ gate_w2,  // (33)
                       ushort* __restrict__ htb,
                       float* __restrict__ gi2, float* __restrict__ gj2) {
    __shared__ uint  s_eb[CAP];                       // packed (ew<<14)|src
    __shared__ float s_coef[CAP * 16];                // 6 KB
    __shared__ float s_gi[16];
    __shared__ __align__(16) float s_x[16][36];       // row 144B: b128-able
    __shared__ __align__(16) float s_feat[16][36];
    __shared__ __align__(16) float s_wmT[16 * 68];    // [o][kk], row 272B

    int n = blockIdx.x;
    int tid = threadIdx.x;

    int cnt = bcount[n];
    int deg = cnt < CAP ? cnt : CAP;
    if (tid < CAP / 4)
        ((uint4*)s_eb)[tid] = ((const uint4*)(bucket + (size_t)n * CAP))[tid];
    {   // w1T staging: 256 float4 loads (was 1024 scalar)
        int o = tid >> 4, k4 = tid & 15;
        *(float4*)&s_wmT[o * 68 + k4 * 4] = ((const float4*)w1T)[o * 16 + k4];
    }
    if (tid < 128) {
        int b = tid >> 3, q = tid & 7;
        *(float4*)&s_x[b][q * 4] = ((const float4*)(X + ((size_t)b * N + n) * 32))[q];
    }
    if (tid < 16) s_gi[tid] = gi[n * 16 + tid] + gate_b[0];
    __syncthreads();

    // Phase 1: coef[k][b] = ew * sigmoid(gi + gj + ew*wge + gb). Edge-parallel.
    float wge = gate_w[64];
    for (int p = tid; p < deg * 16; p += 256) {
        int k = p >> 4, b = p & 15;
        uint pr = s_eb[k];
        float w = dec_ew(pr);
        float z = s_gi[b] + gj[(pr & 0x3FFFu) * 16 + b] + w * wge;
        s_coef[p] = w / (1.0f + __expf(-z));
    }
    __syncthreads();

    // Phase 2: gather (uint4 = 8 channels/lane).
    int wv = tid >> 6, l = tid & 63;
    int c8 = l & 3;                        // channel group: 8c8..8c8+7
    int b  = 4 * wv + ((l >> 2) & 3);      // 0..15
    int h  = l >> 4;                       // slot offset 0..3
    uint boff = (uint)b * 4 + c8;          // uint4 idx within 1KB node block (64/blk)
    float a0 = 0.f, a1 = 0.f, a2 = 0.f, a3 = 0.f;
    float a4 = 0.f, a5 = 0.f, a6 = 0.f, a7 = 0.f;
    int k = h;
    for (; k + 4 < deg; k += 8) {          // slots k, k+4
        uint p0 = s_eb[k], p1 = s_eb[k + 4];
        float c0 = s_coef[(k << 4) | b], c1 = s_coef[((k + 4) << 4) | b];
        uint4 u0 = xt4[(p0 & 0x3FFFu) * 64u + boff];
        uint4 u1 = xt4[(p1 & 0x3FFFu) * 64u + boff];
        a0 += c0 * bf2f_lo(u0.x) + c1 * bf2f_lo(u1.x);
        a1 += c0 * bf2f_hi(u0.x) + c1 * bf2f_hi(u1.x);
        a2 += c0 * bf2f_lo(u0.y) + c1 * bf2f_lo(u1.y);
        a3 += c0 * bf2f_hi(u0.y) + c1 * bf2f_hi(u1.y);
        a4 += c0 * bf2f_lo(u0.z) + c1 * bf2f_lo(u1.z);
        a5 += c0 * bf2f_hi(u0.z) + c1 * bf2f_hi(u1.z);
        a6 += c0 * bf2f_lo(u0.w) + c1 * bf2f_lo(u1.w);
        a7 += c0 * bf2f_hi(u0.w) + c1 * bf2f_hi(u1.w);
    }
    if (k < deg) {                         // at most one leftover slot
        uint pr = s_eb[k];
        float cc = s_coef[(k << 4) | b];
        uint4 u = xt4[(pr & 0x3FFFu) * 64u + boff];
        a0 += cc * bf2f_lo(u.x); a1 += cc * bf2f_hi(u.x);
        a2 += cc * bf2f_lo(u.y); a3 += cc * bf2f_hi(u.y);
        a4 += cc * bf2f_lo(u.z); a5 += cc * bf2f_hi(u.z);
        a6 += cc * bf2f_lo(u.w); a7 += cc * bf2f_hi(u.w);
    }
    // reduce over h (lane bits 4,5)
    a0 += __shfl_xor(a0, 16, 64); a0 += __shfl_xor(a0, 32, 64);
    a1 += __shfl_xor(a1, 16, 64); a1 += __shfl_xor(a1, 32, 64);
    a2 += __shfl_xor(a2, 16, 64); a2 += __shfl_xor(a2, 32, 64);
    a3 += __shfl_xor(a3, 16, 64); a3 += __shfl_xor(a3, 32, 64);
    a4 += __shfl_xor(a4, 16, 64); a4 += __shfl_xor(a4, 32, 64);
    a5 += __shfl_xor(a5, 16, 64); a5 += __shfl_xor(a5, 32, 64);
    a6 += __shfl_xor(a6, 16, 64); a6 += __shfl_xor(a6, 32, 64);
    a7 += __shfl_xor(a7, 16, 64); a7 += __shfl_xor(a7, 32, 64);
    if (h == 0) {
        float inv = 1.0f / fmaxf((float)cnt, 1.0f);
        int cb = 8 * c8;
        s_feat[b][cb]     = a0 * amp_w[cb]     * inv;
        s_feat[b][cb + 1] = a1 * amp_w[cb + 1] * inv;
        s_feat[b][cb + 2] = a2 * amp_w[cb + 2] * inv;
        s_feat[b][cb + 3] = a3 * amp_w[cb + 3] * inv;
        s_feat[b][cb + 4] = a4 * amp_w[cb + 4] * inv;
        s_feat[b][cb + 5] = a5 * amp_w[cb + 5] * inv;
        s_feat[b][cb + 6] = a6 * amp_w[cb + 6] * inv;
        s_feat[b][cb + 7] = a7 * amp_w[cb + 7] * inv;
    }
    __syncthreads();

    // Phase 3: dense 64->16 (vectorized LDS), leaky, layer-2 gate dots.
    {
        int o = tid & 15, bb = tid >> 4;
        const float4* wr4 = (const float4*)&s_wmT[o * 68];   // 272B-aligned rows
        const float4* x4  = (const float4*)&s_x[bb][0];      // 144B-aligned rows
        const float4* f4  = (const float4*)&s_feat[bb][0];
        float d = b1[o];
        #pragma unroll
        for (int q = 0; q < 8; ++q) {
            float4 wvv = wr4[q],    xv = x4[q];
            float4 wf = wr4[8 + q], fv = f4[q];
            d += xv.x * wvv.x + xv.y * wvv.y + xv.z * wvv.z + xv.w * wvv.w;
            d += fv.x * wf.x + fv.y * wf.y + fv.z * wf.z + fv.w * wf.w;
        }
        d = d > 0.0f ? d : 0.01f * d;
        htb[((size_t)n * 16 + bb) * 16 + o] = f2bf(d);
        float pi = d * gate_w2[o];
        float pj = d * gate_w2[16 + o];
        #pragma unroll
        for (int off = 8; off; off >>= 1) {
            pi += __shfl_xor(pi, off, 16);
            pj += __shfl_xor(pj, off, 16);
        }
        if (o == 0) { gi2[n * 16 + bb] = pi; gj2[n * 16 + bb] = pj; }
    }
}

// ---------------------------------------------------------------------------
// Fused layer 2: one node per block, 256 threads, uint4 gather.
// Lane map per wave: c8=l&1 (8ch of 16), b=4*wv+((l>>1)&3), qd=l>>3 (depth 8).
// 8 consecutive lanes cover 128B contiguous per slot.
// ---------------------------------------------------------------------------
__global__ __launch_bounds__(256, 8)
void agg_dense2_kernel(const uint4* __restrict__ htb4,    // bf16x8 (16B)
                       const float* __restrict__ gi,
                       const float* __restrict__ gj,
                       const int* __restrict__ bcount,
                       const uint* __restrict__ bucket,
                       const float* __restrict__ gate_w,   // (33), [32]=wge
                       const float* __restrict__ gate_b,
                       const float* __restrict__ amp_w,    // (16)
                       const float* __restrict__ w2T,      // (32,32) [o][kk]
                       const float* __restrict__ b2,       // (32)
                       float* __restrict__ out) {
    __shared__ uint  s_eb[CAP];
    __shared__ float s_coef[CAP * 16];
    __shared__ float s_gi[16];
    __shared__ __align__(16) float s_x[16][20];       // row 80B: b128-able
    __shared__ __align__(16) float s_feat[16][20];
    __shared__ __align__(16) float s_wmT[32 * 36];    // [o][kk], row 144B

    int n = blockIdx.x;
    int tid = threadIdx.x;

    int cnt = bcount[n];
    int deg = cnt < CAP ? cnt : CAP;
    if (tid < CAP / 4)
        ((uint4*)s_eb)[tid] = ((const uint4*)(bucket + (size_t)n * CAP))[tid];
    {   // w2T staging: 256 float4 loads (was 1024 scalar)
        int o = tid >> 3, k4 = tid & 7;
        *(float4*)&s_wmT[o * 36 + k4 * 4] = ((const float4*)w2T)[o * 8 + k4];
    }
    if (tid < 32) {   // self features: 32 uint4 loads, decode to fp32 LDS
        uint4 u = htb4[(size_t)n * 32 + tid];
        int b = tid >> 1, cb = (tid & 1) * 8;
        float4 f0, f1;
        f0.x = bf2f_lo(u.x); f0.y = bf2f_hi(u.x);
        f0.z = bf2f_lo(u.y); f0.w = bf2f_hi(u.y);
        f1.x = bf2f_lo(u.z); f1.y = bf2f_hi(u.z);
        f1.z = bf2f_lo(u.w); f1.w = bf2f_hi(u.w);
        *(float4*)&s_x[b][cb]     = f0;
        *(float4*)&s_x[b][cb + 4] = f1;
    }
    if (tid < 16) s_gi[tid] = gi[n * 16 + tid] + gate_b[0];
    __syncthreads();

    float wge = gate_w[32];
    for (int p = tid; p < deg * 16; p += 256) {
        int k = p >> 4, b = p & 15;
        uint pr = s_eb[k];
        float w = dec_ew(pr);
        float z = s_gi[b] + gj[(pr & 0x3FFFu) * 16 + b] + w * wge;
        s_coef[p] = w / (1.0f + __expf(-z));
    }
    __syncthreads();

    // Gather: c8=l&1, b=4*wv+((l>>1)&3), qd=l>>3 (slot depth 8).
    int wv = tid >> 6, l = tid & 63;
    int c8 = l & 1;                        // channel group: 8c8..8c8+7
    int b  = 4 * wv + ((l >> 1) & 3);      // 0..15
    int qd = l >> 3;                       // slot offset 0..7
    uint boff = (uint)b * 2 + c8;          // uint4 idx within 512B node block (32/blk)
    float a0 = 0.f, a1 = 0.f, a2 = 0.f, a3 = 0.f;
    float a4 = 0.f, a5 = 0.f, a6 = 0.f, a7 = 0.f;
    int k = qd;
    for (; k + 8 < deg; k += 16) {         // slots k, k+8
        uint p0 = s_eb[k], p1 = s_eb[k + 8];
        float c0 = s_coef[(k << 4) | b], c1 = s_coef[((k + 8) << 4) | b];
        uint4 u0 = htb4[(p0 & 0x3FFFu) * 32u + boff];
        uint4 u1 = htb4[(p1 & 0x3FFFu) * 32u + boff];
        a0 += c0 * bf2f_lo(u0.x) + c1 * bf2f_lo(u1.x);
        a1 += c0 * bf2f_hi(u0.x) + c1 * bf2f_hi(u1.x);
        a2 += c0 * bf2f_lo(u0.y) + c1 * bf2f_lo(u1.y);
        a3 += c0 * bf2f_hi(u0.y) + c1 * bf2f_hi(u1.y);
        a4 += c0 * bf2f_lo(u0.z) + c1 * bf2f_lo(u1.z);
        a5 += c0 * bf2f_hi(u0.z) + c1 * bf2f_hi(u1.z);
        a6 += c0 * bf2f_lo(u0.w) + c1 * bf2f_lo(u1.w);
        a7 += c0 * bf2f_hi(u0.w) + c1 * bf2f_hi(u1.w);
    }
    if (k < deg) {                         // at most one leftover slot
        uint pr = s_eb[k];
        float cc = s_coef[(k << 4) | b];
        uint4 u = htb4[(pr & 0x3FFFu) * 32u + boff];
        a0 += cc * bf2f_lo(u.x); a1 += cc * bf2f_hi(u.x);
        a2 += cc * bf2f_lo(u.y); a3 += cc * bf2f_hi(u.y);
        a4 += cc * bf2f_lo(u.z); a5 += cc * bf2f_hi(u.z);
        a6 += cc * bf2f_lo(u.w); a7 += cc * bf2f_hi(u.w);
    }
    // reduce over qd (lane bits 3,4,5)
    a0 += __shfl_xor(a0, 8, 64); a0 += __shfl_xor(a0, 16, 64); a0 += __shfl_xor(a0, 32, 64);
    a1 += __shfl_xor(a1, 8, 64); a1 += __shfl_xor(a1, 16, 64); a1 += __shfl_xor(a1, 32, 64);
    a2 += __shfl_xor(a2, 8, 64); a2 += __shfl_xor(a2, 16, 64); a2 += __shfl_xor(a2, 32, 64);
    a3 += __shfl_xor(a3, 8, 64); a3 += __shfl_xor(a3, 16, 64); a3 += __shfl_xor(a3, 32, 64);
    a4 += __shfl_xor(a4, 8, 64); a4 += __shfl_xor(a4, 16, 64); a4 += __shfl_xor(a4, 32, 64);
    a5 += __shfl_xor(a5, 8, 64); a5 += __shfl_xor(a5, 16, 64); a5 += __shfl_xor(a5, 32, 64);
    a6 += __shfl_xor(a6, 8, 64); a6 += __shfl_xor(a6, 16, 64); a6 += __shfl_xor(a6, 32, 64);
    a7 += __shfl_xor(a7, 8, 64); a7 += __shfl_xor(a7, 16, 64); a7 += __shfl_xor(a7, 32, 64);
    if (qd == 0) {
        float inv = 1.0f / fmaxf((float)cnt, 1.0f);
        int cb = 8 * c8;
        s_feat[b][cb]     = a0 * amp_w[cb]     * inv;
        s_feat[b][cb + 1] = a1 * amp_w[cb + 1] * inv;
        s_feat[b][cb + 2] = a2 * amp_w[cb + 2] * inv;
        s_feat[b][cb + 3] = a3 * amp_w[cb + 3] * inv;
        s_feat[b][cb + 4] = a4 * amp_w[cb + 4] * inv;
        s_feat[b][cb + 5] = a5 * amp_w[cb + 5] * inv;
        s_feat[b][cb + 6] = a6 * amp_w[cb + 6] * inv;
        s_feat[b][cb + 7] = a7 * amp_w[cb + 7] * inv;
    }
    __syncthreads();

    // Dense 32->32; thread (bb, o2) produces channels (2*o2, 2*o2+1) -> float2.
    {
        int o2 = tid & 15, bb = tid >> 4;
        const float4* wr0 = (const float4*)&s_wmT[(2 * o2) * 36];
        const float4* wr1 = (const float4*)&s_wmT[(2 * o2 + 1) * 36];
        const float4* x4  = (const float4*)&s_x[bb][0];
        const float4* f4  = (const float4*)&s_feat[bb][0];
        float d0 = b2[2 * o2], d1 = b2[2 * o2 + 1];
        #pragma unroll
        for (int q = 0; q < 4; ++q) {
            float4 xv = x4[q], fv = f4[q];
            float4 w0a = wr0[q], w0b = wr0[4 + q];
            float4 w1a = wr1[q], w1b = wr1[4 + q];
            d0 += xv.x * w0a.x + xv.y * w0a.y + xv.z * w0a.z + xv.w * w0a.w;
            d0 += fv.x * w0b.x + fv.y * w0b.y + fv.z * w0b.z + fv.w * w0b.w;
            d1 += xv.x * w1a.x + xv.y * w1a.y + xv.z * w1a.z + xv.w * w1a.w;
            d1 += fv.x * w1b.x + fv.y * w1b.y + fv.z * w1b.z + fv.w * w1b.w;
        }
        size_t ob = ((size_t)bb * N + n) * 32;
        float2 r; r.x = d0; r.y = d1;
        *(float2*)(out + ob + 2 * o2) = r;
    }
}

// ---------------------------------------------------------------------------
extern "C" void kernel_launch(void* const* d_in, const int* in_sizes, int n_in,
                              void* d_out, int out_size, void* d_ws, size_t ws_size,
                              hipStream_t stream) {
    const float* X       = (const float*)d_in[0];
    const int*   ei1     = (const int*)  d_in[1];   // src=ei1, dst=ei1+E
    const float* ew1     = (const float*)d_in[2];
    const int*   ei2     = (const int*)  d_in[4];
    const float* ew2     = (const float*)d_in[5];
    const float* amp_w1  = (const float*)d_in[7];
    const float* gate_w1 = (const float*)d_in[8];
    const float* gate_b1 = (const float*)d_in[9];
    const float* w1      = (const float*)d_in[10];
    const float* b1      = (const float*)d_in[11];
    const float* amp_w2  = (const float*)d_in[12];
    const float* gate_w2 = (const float*)d_in[13];
    const float* gate_b2 = (const float*)d_in[14];
    const float* w2      = (const float*)d_in[15];
    const float* b2      = (const float*)d_in[16];
    float* out = (float*)d_out;

    // ws layout
    char* p = (char*)d_ws;
    ushort* xt     = (ushort*)p; p += (size_t)N * B * 32 * sizeof(ushort); // 10.24 MB
    ushort* htb    = (ushort*)p; p += (size_t)N * B * 16 * sizeof(ushort); // 5.12 MB
    float* gi1     = (float*)p;  p += (size_t)N * B * sizeof(float);
    float* gj1     = (float*)p;  p += (size_t)N * B * sizeof(float);
    float* gi2     = (float*)p;  p += (size_t)N * B * sizeof(float);
    float* gj2     = (float*)p;  p += (size_t)N * B * sizeof(float);
    uint*  bucket1 = (uint*)p;   p += (size_t)N * CAP * sizeof(uint);      // 3.84 MB
    uint*  bucket2 = (uint*)p;   p += (size_t)N * CAP * sizeof(uint);      // 3.84 MB
    int*   bcount1 = (int*)p;    p += (size_t)N * sizeof(int);
    int*   bcount2 = (int*)p;    p += (size_t)N * sizeof(int);
    float* w1T     = (float*)p;  p += 1024 * sizeof(float);
    float* w2T     = (float*)p;  p += 1024 * sizeof(float);

    hipMemsetAsync(bcount1, 0, 2 * (size_t)N * sizeof(int), stream);
    prep_bucket_kernel<<<2048, 256, 0, stream>>>(
        X, gate_w1, ei1, ew1, ei2, ew2, w1, w2, xt, gi1, gj1, w1T, w2T,
        bcount1, bucket1, bcount2, bucket2);

    agg_dense1_kernel<<<N, 256, 0, stream>>>(
        X, (const uint4*)xt, gi1, gj1, bcount1, bucket1,
        gate_w1, gate_b1, amp_w1, w1T, b1, gate_w2, htb, gi2, gj2);

    agg_dense2_kernel<<<N, 256, 0, stream>>>(
        (const uint4*)htb, gi2, gj2, bcount2, bucket2,
        gate_w2, gate_b2, amp_w2, w2T, b2, out);
}